// Round 9
// baseline (75.444 us; speedup 1.0000x reference)
//
#include <hip/hip_runtime.h>

// SmoothnessLoss: smooth[i] = sum_{j<64} |x[i+j] - mean_j(x[i+j])| for both inputs,
// out = mean((smoothHat - smoothY)^2) over W = N-k-1 windows. k fixed at 64.
//
// R9 = composite of every proven piece:
//  - LDS staging (R2/R4): contiguous coalesced global->LDS, 8.5 MB instead of
//    R7/R8's 136 MB of stride-32B L1 traffic (direct-global loads touch 2KB
//    span per 1KB delivered at C=8).
//  - wave-split (R7/R8): waves 0-1 yHat, waves 2-3 y -> ONE e[72] buffer/thread
//    (~110 VGPR natural, 4 waves/SIMD). No forced launch_bounds cap (R5 spill).
//  - C=8 windows/thread, 1024 windows/block, 977 blocks (best grid shape).
//  - per-block plain store to d_ws + tiny final kernel (R8: killed the
//    same-address atomicAdd serialization, -6us).
// HARD-WON (R3): e[] promotion needs fully-unrolled code with constant
// private-array indices; runtime LDS base/offset is fine (ds vaddr is runtime
// anyway), runtime PRIVATE indices are not.

#define K     64
#define C     8                  // windows per thread
#define HALF  128                // threads per array half
#define BLK   (2 * HALF)
#define WPB   (HALF * C)         // 1024 windows per block
#define TILE  (WPB + K)          // 1088 floats staged per array
#define TILE4 (TILE / 4)         // 272 float4 per array
#define NLD   ((K + C) / 4)      // 18 b128 LDS reads per thread (e[72])

__global__ __launch_bounds__(BLK) void smoothness_partial_kernel(
    const float* __restrict__ yHat, const float* __restrict__ y,
    float* __restrict__ ws, int N, int W)
{
    __shared__ __align__(16) float4 tile[2][TILE4];   // 8.5 KB: [0]=yHat, [1]=y
    __shared__ __align__(16) float4 xch[2 * HALF];    // y-half's d[8] (4 KB)
    __shared__ float wave_sums[BLK / 64];

    const int base = blockIdx.x * WPB;           // float index, multiple of 1024
    const int tid  = threadIdx.x;
    const int half = __builtin_amdgcn_readfirstlane(tid >> 7);  // wave-uniform
    const int lt   = tid & (HALF - 1);
    const int w0   = base + lt * C;

    // Stage this half's array: 272 float4 with 128 threads, 3 rounds, contiguous
    // lanes -> perfectly coalesced 16B/lane global loads. Zero-fill past N.
    {
        const float* g   = half ? y : yHat;      // SGPR base select
        const float4* gp = (const float4*)g + (base >> 2);
        const int g4max  = (N - base) >> 2;      // N % 4 == 0, base < N always
        #pragma unroll
        for (int r = 0; r < 3; ++r) {
            const int pos = lt + r * HALF;
            if (pos < TILE4) {
                float4 v = make_float4(0.f, 0.f, 0.f, 0.f);
                if (pos < g4max) v = gp[pos];    // OOB floats only feed discarded
                tile[half][pos] = v;             // windows (>= W)
            }
        }
    }
    __syncthreads();

    // LDS -> registers: 18 x ds_read_b128, lane stride 32B (~2x conflict-free
    // b128 rate -- inherent to overlapping-window sharing, still ~2.7us total).
    float e[K + C];
    {
        const float4* p = &tile[half][0] + 2 * lt;
        #pragma unroll
        for (int j = 0; j < NLD; ++j) {
            float4 t = p[j];
            e[4 * j + 0] = t.x; e[4 * j + 1] = t.y;
            e[4 * j + 2] = t.z; e[4 * j + 3] = t.w;
        }
    }

    // window-0 sum: 4 independent partials
    float a0 = 0.f, a1 = 0.f, a2 = 0.f, a3 = 0.f;
    #pragma unroll
    for (int j = 0; j < K; j += 4) {
        a0 += e[j + 0]; a1 += e[j + 1]; a2 += e[j + 2]; a3 += e[j + 3];
    }
    float sums[C];
    sums[0] = (a0 + a1) + (a2 + a3);
    #pragma unroll
    for (int c = 1; c < C; ++c)
        sums[c] = sums[c - 1] + (e[K + c - 1] - e[c - 1]);

    // abs-dev per window (fabs folds into src modifier)
    float d[C];
    #pragma unroll
    for (int c = 0; c < C; ++c) {
        const float m = sums[c] * (1.0f / K);
        float d0 = 0.f, d1 = 0.f, d2 = 0.f, d3 = 0.f;
        #pragma unroll
        for (int j = 0; j < K; j += 4) {
            d0 += fabsf(e[c + j + 0] - m);
            d1 += fabsf(e[c + j + 1] - m);
            d2 += fabsf(e[c + j + 2] - m);
            d3 += fabsf(e[c + j + 3] - m);
        }
        d[c] = (d0 + d1) + (d2 + d3);
    }

    // y-half hands its 8 smoothness values to the yHat-half
    float part = 0.f;
    if (half) {
        xch[2 * lt + 0] = make_float4(d[0], d[1], d[2], d[3]);
        xch[2 * lt + 1] = make_float4(d[4], d[5], d[6], d[7]);
    }
    __syncthreads();
    if (!half) {
        const float4 b0 = xch[2 * lt + 0];
        const float4 b1 = xch[2 * lt + 1];
        const float dB[C] = {b0.x, b0.y, b0.z, b0.w, b1.x, b1.y, b1.z, b1.w};
        #pragma unroll
        for (int c = 0; c < C; ++c) {
            if (w0 + c < W) {
                const float diff = d[c] - dB[c];
                part += diff * diff;
            }
        }
    }

    // wave-64 shuffle reduction -> per-wave LDS -> ONE PLAIN STORE per block
    #pragma unroll
    for (int off = 32; off > 0; off >>= 1)
        part += __shfl_down(part, off, 64);

    const int lane = tid & 63;
    const int wv   = tid >> 6;
    if (lane == 0) wave_sums[wv] = part;
    __syncthreads();

    if (tid == 0) {
        float ssum = 0.f;
        #pragma unroll
        for (int i = 0; i < BLK / 64; ++i) ssum += wave_sums[i];
        ws[blockIdx.x] = ssum;                   // distinct address: no contention
    }
}

__global__ __launch_bounds__(256) void smoothness_final_kernel(
    const float* __restrict__ ws, float* __restrict__ out, int nb, float invW)
{
    __shared__ float wave_sums[4];
    const int tid = threadIdx.x;

    float s = 0.f;
    for (int i = tid; i < nb; i += 256) s += ws[i];

    #pragma unroll
    for (int off = 32; off > 0; off >>= 1)
        s += __shfl_down(s, off, 64);

    if ((tid & 63) == 0) wave_sums[tid >> 6] = s;
    __syncthreads();

    if (tid == 0) {
        float t = (wave_sums[0] + wave_sums[1]) + (wave_sums[2] + wave_sums[3]);
        out[0] = t * invW;                       // pure store: no d_out memset needed
    }
}

extern "C" void kernel_launch(void* const* d_in, const int* in_sizes, int n_in,
                              void* d_out, int out_size, void* d_ws, size_t ws_size,
                              hipStream_t stream) {
    const float* yHat = (const float*)d_in[0];
    const float* y    = (const float*)d_in[1];
    float* out        = (float*)d_out;
    float* ws         = (float*)d_ws;

    const int N = in_sizes[0];     // 1,000,000
    const int W = N - K - 1;       // 999,935
    const float invW = 1.0f / (float)W;

    const int grid = (W + WPB - 1) / WPB;           // 977 blocks
    smoothness_partial_kernel<<<grid, BLK, 0, stream>>>(yHat, y, ws, N, W);
    smoothness_final_kernel<<<1, 256, 0, stream>>>(ws, out, grid, invW);
}